// Round 9
// baseline (64.962 us; speedup 1.0000x reference)
//
#include <hip/hip_runtime.h>
#include <math.h>

#define T_TOK 8192
#define HDIM 4096
#define NSLOT 128
#define KRET 4
#define TOPK 2048
#define ALPHA 0.1f
#define MAXC 2048   // hard bound: a slot appears at most once per selected token

// ---------------- Kernel 1: per-token importance, one wave per token ----------
__global__ __launch_bounds__(256) void importance_kernel(
    const float* __restrict__ h, const float* __restrict__ attn,
    const float* __restrict__ W, const float* __restrict__ b,
    float* __restrict__ imp)
{
    const int wid  = threadIdx.x >> 6;
    const int lane = threadIdx.x & 63;
    const int t = blockIdx.x * 4 + wid;
    const float4* hv = reinterpret_cast<const float4*>(h + (size_t)t * HDIM);
    const float4* Wv = reinterpret_cast<const float4*>(W);
    float sumsq = 0.f, dot = 0.f;
    #pragma unroll 4
    for (int i = 0; i < 16; i++) {
        float4 x = hv[lane + i * 64];
        float4 w = Wv[lane + i * 64];
        sumsq += x.x * x.x + x.y * x.y + x.z * x.z + x.w * x.w;
        dot   += x.x * w.x + x.y * w.y + x.z * w.z + x.w * w.w;
    }
    #pragma unroll
    for (int off = 32; off > 0; off >>= 1) {
        sumsq += __shfl_down(sumsq, off);
        dot   += __shfl_down(dot, off);
    }
    if (lane == 0) {
        float mag = sqrtf(sumsq);
        float ent = 0.f;
        #pragma unroll
        for (int k = 0; k < KRET; k++) {
            float a = attn[t * KRET + k];
            ent -= a * logf(a + 1e-8f);
        }
        float surprise = ent / logf(4.0f);
        float score = dot + b[0];
        float sig = 1.0f / (1.0f + expf(-score));
        // importance > 0 always (mag,surprise >= 0; sig > 0) -> uint bits monotonic
        imp[t] = mag * (1.0f + surprise) + sig;
    }
}

// ---------------- Kernel 2: radix-select threshold + per-slot CSR list -------
// One block per slot. Each block redundantly radix-selects the TOPK-th largest
// importance (exact bits), then builds its slot's member-token list with
// jax.lax.top_k tie semantics (value desc, index asc). Fully deterministic.
__global__ __launch_bounds__(256) void selectlist_kernel(
    const float* __restrict__ imp, const int* __restrict__ si,
    int* __restrict__ lists, int* __restrict__ counts)
{
    const int slot = blockIdx.x;
    const int tid  = threadIdx.x;
    __shared__ unsigned s_u[T_TOK];   // 32 KB: importance bits
    __shared__ int s_hist[256];
    __shared__ int s_scan[256];
    __shared__ unsigned s_prefix;
    __shared__ int s_want;

    for (int i = tid; i < T_TOK; i += 256)
        s_u[i] = __float_as_uint(imp[i]);
    if (tid == 0) { s_prefix = 0u; s_want = TOPK; }
    __syncthreads();

    // 4 passes, 8 bits each, top-down. Invariant: among values whose high bits
    // match s_prefix, we want the s_want-th largest.
    for (int pass = 0; pass < 4; pass++) {
        const int p = 24 - pass * 8;
        const unsigned himask = (pass == 0) ? 0u : (0xFFFFFFFFu << (p + 8));
        const unsigned pref = s_prefix;
        const int want = s_want;
        s_hist[tid] = 0;
        __syncthreads();
        for (int j = tid; j < T_TOK; j += 256) {
            unsigned u = s_u[j];
            if ((u & himask) == pref) atomicAdd(&s_hist[(u >> p) & 255], 1);
        }
        __syncthreads();
        // suffix sum: s_scan[b] = sum_{i>=b} hist[i]
        s_scan[tid] = s_hist[tid];
        __syncthreads();
        for (int off = 1; off < 256; off <<= 1) {
            int add = (tid + off < 256) ? s_scan[tid + off] : 0;
            __syncthreads();
            s_scan[tid] += add;
            __syncthreads();
        }
        int sufb  = s_scan[tid];
        int sufb1 = (tid < 255) ? s_scan[tid + 1] : 0;
        if (sufb >= want && sufb1 < want) {   // exactly one thread
            s_prefix = pref | ((unsigned)tid << p);
            s_want = want - sufb1;            // rank within chosen bin
        }
        __syncthreads();
    }
    const unsigned thr = s_prefix;      // exact bits of the TOPK-th largest
    const int ties_allowed = s_want;    // # of ==thr values to take (lowest idx)

    // tie prefix: # of tokens s < t with imp[s] == thr
    const int base = tid * 32;
    int eqcnt = 0;
    #pragma unroll 8
    for (int j = 0; j < 32; j++) eqcnt += (s_u[base + j] == thr);
    __syncthreads();
    s_scan[tid] = eqcnt;
    __syncthreads();
    for (int off = 1; off < 256; off <<= 1) {
        int v = s_scan[tid];
        int add = (tid >= off) ? s_scan[tid - off] : 0;
        __syncthreads();
        s_scan[tid] = v + add;
        __syncthreads();
    }
    const int tie_base = s_scan[tid] - eqcnt;  // exclusive prefix

    // selection + slot membership, 32 consecutive tokens per thread
    const int4* si4 = reinterpret_cast<const int4*>(si);
    unsigned mask = 0;
    int local = 0;
    int trun = tie_base;
    #pragma unroll 8
    for (int j = 0; j < 32; j++) {
        const int t = base + j;
        unsigned u = s_u[t];
        bool sel = (u > thr) || (u == thr && trun < ties_allowed);
        if (u == thr) trun++;
        int4 s = si4[t];
        bool mem = (s.x == slot) | (s.y == slot) | (s.z == slot) | (s.w == slot);
        if (sel && mem) { mask |= (1u << j); local++; }
    }
    __syncthreads();
    s_scan[tid] = local;   // reuse for list-position scan
    __syncthreads();
    for (int off = 1; off < 256; off <<= 1) {
        int v = s_scan[tid];
        int add = (tid >= off) ? s_scan[tid - off] : 0;
        __syncthreads();
        s_scan[tid] = v + add;
        __syncthreads();
    }
    int pos = s_scan[tid] - local;  // exclusive prefix (ascending t -> deterministic)
    int* mylist = lists + (size_t)slot * MAXC;
    for (int j = 0; j < 32; j++) {
        if (mask & (1u << j)) mylist[pos++] = base + j;
    }
    if (tid == 255) counts[slot] = s_scan[255];
}

// ---------------- Kernel 3: CSR gather + segment-mean + EMA ----------------
__global__ __launch_bounds__(256) void update_kernel(
    const float* __restrict__ h, const float* __restrict__ mem,
    const int* __restrict__ lists, const int* __restrict__ counts,
    float* __restrict__ out)
{
    const int slot = blockIdx.x >> 2;   // 128 slots
    const int chunk = blockIdx.x & 3;   // 4 chunks of 1024 floats
    const int cnt = counts[slot];
    __shared__ int s_list[MAXC];
    for (int i = threadIdx.x; i < cnt; i += 256)
        s_list[i] = lists[(size_t)slot * MAXC + i];
    __syncthreads();

    const int dbase = chunk * 1024 + threadIdx.x * 4;
    float4 acc = make_float4(0.f, 0.f, 0.f, 0.f);
    int i = 0;
    for (; i + 4 <= cnt; i += 4) {
        int t0 = s_list[i], t1 = s_list[i + 1];
        int t2 = s_list[i + 2], t3 = s_list[i + 3];
        float4 x0 = *reinterpret_cast<const float4*>(h + (size_t)t0 * HDIM + dbase);
        float4 x1 = *reinterpret_cast<const float4*>(h + (size_t)t1 * HDIM + dbase);
        float4 x2 = *reinterpret_cast<const float4*>(h + (size_t)t2 * HDIM + dbase);
        float4 x3 = *reinterpret_cast<const float4*>(h + (size_t)t3 * HDIM + dbase);
        acc.x += x0.x + x1.x + x2.x + x3.x;
        acc.y += x0.y + x1.y + x2.y + x3.y;
        acc.z += x0.z + x1.z + x2.z + x3.z;
        acc.w += x0.w + x1.w + x2.w + x3.w;
    }
    for (; i < cnt; i++) {
        int t0 = s_list[i];
        float4 x0 = *reinterpret_cast<const float4*>(h + (size_t)t0 * HDIM + dbase);
        acc.x += x0.x; acc.y += x0.y; acc.z += x0.z; acc.w += x0.w;
    }

    const size_t o = (size_t)slot * HDIM + dbase;
    float4 cur = *reinterpret_cast<const float4*>(mem + o);
    float4 r;
    if (cnt > 0) {
        float inv = 1.0f / (float)cnt;
        r.x = ALPHA * (acc.x * inv) + (1.f - ALPHA) * cur.x;
        r.y = ALPHA * (acc.y * inv) + (1.f - ALPHA) * cur.y;
        r.z = ALPHA * (acc.z * inv) + (1.f - ALPHA) * cur.z;
        r.w = ALPHA * (acc.w * inv) + (1.f - ALPHA) * cur.w;
    } else {
        r = cur;
    }
    *reinterpret_cast<float4*>(out + o) = r;
}

extern "C" void kernel_launch(void* const* d_in, const int* in_sizes, int n_in,
                              void* d_out, int out_size, void* d_ws, size_t ws_size,
                              hipStream_t stream) {
    const float* h    = (const float*)d_in[0];  // [8192, 4096]
    const float* attn = (const float*)d_in[1];  // [8192, 4]
    const int*   si   = (const int*)d_in[2];    // [8192, 4]
    const float* mem  = (const float*)d_in[3];  // [1, 128, 4096]
    const float* W    = (const float*)d_in[4];  // [1, 4096]
    const float* b    = (const float*)d_in[5];  // [1]
    float* out = (float*)d_out;                 // [1, 128, 4096]

    char* ws = (char*)d_ws;
    float* imp    = (float*)(ws);            // 8192 f32
    int*   counts = (int*)(ws + 65536);      // 128 i32
    int*   lists  = (int*)(ws + 131072);     // 128 x 2048 i32 (1 MB)

    importance_kernel<<<T_TOK / 4, 256, 0, stream>>>(h, attn, W, b, imp);
    selectlist_kernel<<<NSLOT, 256, 0, stream>>>(imp, si, lists, counts);
    update_kernel<<<NSLOT * 4, 256, 0, stream>>>(h, mem, lists, counts, out);
}